// Round 1
// baseline (10.996 us; speedup 1.0000x reference)
//
#include <hip/hip_runtime.h>

// BP-MLL pairwise exponential ranking loss, factorized:
//   pair_sums[b] = (sum_{j in neg} exp(o_j)) * (sum_{i in pos} exp(-o_i))
//   y_norm[b]    = n_pos * (C - n_pos)
//   out          = sum_b pair_sums[b] / y_norm[b] / B
// O(B*C) streaming reduction instead of the reference's O(B*C^2).

namespace {

constexpr int kB = 32;
constexpr int kC = 2048;

__global__ __launch_bounds__(256) void bpmll_per_sample(
    const float* __restrict__ inp, const int* __restrict__ tgt,
    float* __restrict__ ws) {
  const int b = blockIdx.x;
  const int t = threadIdx.x;
  const float4* xv = reinterpret_cast<const float4*>(inp + b * kC);
  const int4*   yv = reinterpret_cast<const int4*>(tgt + b * kC);

  float s_neg = 0.f;   // sum over negatives of exp(x)
  float s_pos = 0.f;   // sum over positives of exp(-x)
  float n_pos = 0.f;   // count of positives

#pragma unroll
  for (int k = 0; k < 2; ++k) {
    const float4 x = xv[t + k * 256];
    const int4   y = yv[t + k * 256];
    if (y.x == 1) { s_pos += __expf(-x.x); n_pos += 1.f; } else { s_neg += __expf(x.x); }
    if (y.y == 1) { s_pos += __expf(-x.y); n_pos += 1.f; } else { s_neg += __expf(x.y); }
    if (y.z == 1) { s_pos += __expf(-x.z); n_pos += 1.f; } else { s_neg += __expf(x.z); }
    if (y.w == 1) { s_pos += __expf(-x.w); n_pos += 1.f; } else { s_neg += __expf(x.w); }
  }

  // wave-64 shuffle reduction
#pragma unroll
  for (int off = 32; off > 0; off >>= 1) {
    s_neg += __shfl_down(s_neg, off);
    s_pos += __shfl_down(s_pos, off);
    n_pos += __shfl_down(n_pos, off);
  }

  __shared__ float red[3][4];
  const int wid = t >> 6;
  if ((t & 63) == 0) { red[0][wid] = s_neg; red[1][wid] = s_pos; red[2][wid] = n_pos; }
  __syncthreads();

  if (t == 0) {
    float sn = 0.f, sp = 0.f, npos = 0.f;
#pragma unroll
    for (int w = 0; w < 4; ++w) { sn += red[0][w]; sp += red[1][w]; npos += red[2][w]; }
    const float nneg = (float)kC - npos;
    ws[b] = (sn * sp) / (npos * nneg * (float)kB);
  }
}

__global__ __launch_bounds__(64) void bpmll_final(
    const float* __restrict__ ws, float* __restrict__ out) {
  const int t = threadIdx.x;
  float v = (t < kB) ? ws[t] : 0.f;
#pragma unroll
  for (int off = 32; off > 0; off >>= 1) v += __shfl_down(v, off);
  if (t == 0) out[0] = v;
}

}  // namespace

extern "C" void kernel_launch(void* const* d_in, const int* in_sizes, int n_in,
                              void* d_out, int out_size, void* d_ws, size_t ws_size,
                              hipStream_t stream) {
  const float* inp = (const float*)d_in[0];
  const int*   tgt = (const int*)d_in[1];
  float* ws  = (float*)d_ws;   // 32 floats of scratch, rewritten every call
  float* out = (float*)d_out;

  bpmll_per_sample<<<kB, 256, 0, stream>>>(inp, tgt, ws);
  bpmll_final<<<1, 64, 0, stream>>>(ws, out);
}